// Round 4
// baseline (343.822 us; speedup 1.0000x reference)
//
#include <hip/hip_runtime.h>

#define NBINS 1024
#define BPB   128
#define TPB   256
#define NB    8
#define LCAP  512
#define PCAP  8192
#define SCAP  4096

static __device__ __forceinline__ unsigned bucketOf(float v) {
    unsigned b = (unsigned)(v * (float)NBINS);
    return b > (NBINS - 1) ? (NBINS - 1) : b;
}

// ---------- pass 1: reg-dbuf streaming; LDS hist -> per-block u16 replicas ----------
__global__ __launch_bounds__(TPB, 4) void k_pass1(const float* __restrict__ pred,
                                                  const float* __restrict__ targ,
                                                  int nvec,
                                                  unsigned short* __restrict__ hist16,
                                                  double* __restrict__ sse,
                                                  unsigned* __restrict__ nvalid)
{
    __shared__ unsigned h[2 * NBINS];
    for (int i = threadIdx.x; i < 2 * NBINS; i += TPB) h[i] = 0u;
    __syncthreads();

    const int b = blockIdx.y;
    const float4* __restrict__ p4 = (const float4*)pred + (size_t)b * nvec;
    const float4* __restrict__ t4 = (const float4*)targ + (size_t)b * nvec;

    float    lsse = 0.f;
    unsigned lnv = 0, lnp = 0;
    const int S = BPB * TPB;

#define P1_PROC(tq, pq)                                          \
    {                                                            \
        float tv[4] = {tq.x, tq.y, tq.z, tq.w};                  \
        float pv[4] = {pq.x, pq.y, pq.z, pq.w};                  \
        _Pragma("unroll")                                        \
        for (int j = 0; j < 4; ++j) {                            \
            float tt = tv[j], pp = pv[j];                        \
            if (tt > 0.01f) {                                    \
                float d = pp - tt;                               \
                lsse += d * d; lnv++;                            \
                atomicAdd(&h[bucketOf(tt)], 1u);                 \
                if (pp > 0.f) {                                  \
                    lnp++;                                       \
                    atomicAdd(&h[NBINS + bucketOf(pp)], 1u);     \
                }                                                \
            }                                                    \
        }                                                        \
    }

    int i = blockIdx.x * TPB + threadIdx.x;
    float4 cT0, cP0, cT1, cP1;
    cT0 = cP0 = cT1 = cP1 = make_float4(0.f, 0.f, 0.f, 0.f);
    if (i < nvec) {
        cT0 = t4[i]; cP0 = p4[i];
        if (i + S < nvec) { cT1 = t4[i + S]; cP1 = p4[i + S]; }
    }
    while (i < nvec) {
        const int nx = i + 2 * S;
        float4 nT0 = cT0, nP0 = cP0, nT1 = cT1, nP1 = cP1;
        if (nx < nvec)     { nT0 = t4[nx];     nP0 = p4[nx]; }
        if (nx + S < nvec) { nT1 = t4[nx + S]; nP1 = p4[nx + S]; }
        P1_PROC(cT0, cP0);
        if (i + S < nvec) P1_PROC(cT1, cP1);
        cT0 = nT0; cP0 = nP0; cT1 = nT1; cP1 = nP1;
        i = nx;
    }
#undef P1_PROC
    __syncthreads();

    // plain coalesced u16 replica stores — every bin written, no memset needed
    unsigned short* gh = hist16 + ((size_t)b * BPB + blockIdx.x) * (2 * NBINS);
    ushort4* gh4 = (ushort4*)gh;
    for (int k = threadIdx.x; k < (2 * NBINS) / 4; k += TPB) {
        ushort4 v;
        v.x = (unsigned short)h[4 * k + 0];
        v.y = (unsigned short)h[4 * k + 1];
        v.z = (unsigned short)h[4 * k + 2];
        v.w = (unsigned short)h[4 * k + 3];
        gh4[k] = v;
    }

    for (int off = 32; off; off >>= 1) {
        lsse += __shfl_down(lsse, off);
        lnv  += __shfl_down(lnv, off);
        lnp  += __shfl_down(lnp, off);
    }
    if ((threadIdx.x & 63) == 0) {
        atomicAdd(&sse[b], (double)lsse);
        atomicAdd(&nvalid[2 * b + 0], lnv);
        atomicAdd(&nvalid[2 * b + 1], lnp);
    }
}

// ---------- pass 2: sum replicas, locate rank buckets ----------
// binfo per (b,t), 8 u32: [0]=lo [1]=hi [2]=cum_below [3]=k [4]=frac bits [5]=nv
__global__ __launch_bounds__(256) void k_scan(const unsigned short* __restrict__ hist16,
                                              const unsigned* __restrict__ nvalid,
                                              unsigned* __restrict__ binfo)
{
    const int bt = blockIdx.x;  // 0..15
    const int b = bt >> 1, t = bt & 1;
    const unsigned nv = nvalid[bt];
    unsigned* bi = binfo + bt * 8;

    __shared__ unsigned partial[256];
    __shared__ unsigned sk, sr2;

    if (threadIdx.x == 0) {
        bi[5] = nv;
        if (nv == 0) {
            bi[0] = 0xFFFFFFFFu; bi[1] = 0xFFFFFFFFu;
            bi[2] = 0; bi[3] = 0; bi[4] = __float_as_uint(0.0f);
        } else {
            double pos  = 0.9 * (double)(nv - 1);
            unsigned k  = (unsigned)pos;
            double frac = pos - (double)k;
            bi[3] = k;
            bi[4] = __float_as_uint((float)frac);
            sk = k;
            sr2 = (k + 2 <= nv) ? (k + 2) : (k + 1);
        }
    }
    __syncthreads();
    if (nv == 0) return;

    const unsigned r1 = sk + 1, r2 = sr2;

    const int lo = threadIdx.x * (NBINS / 256);  // 4 bins/thread
    unsigned local[NBINS / 256];
#pragma unroll
    for (int j = 0; j < NBINS / 256; ++j) local[j] = 0;
    for (int rep = 0; rep < BPB; ++rep) {
        const ushort4* h4 = (const ushort4*)(hist16 +
            ((size_t)b * BPB + rep) * (2 * NBINS) + (size_t)t * NBINS + lo);
        ushort4 a = h4[0];
        local[0] += a.x; local[1] += a.y; local[2] += a.z; local[3] += a.w;
    }
    unsigned ls = 0;
#pragma unroll
    for (int j = 0; j < NBINS / 256; ++j) ls += local[j];

    partial[threadIdx.x] = ls;
    __syncthreads();
    for (int off = 1; off < 256; off <<= 1) {
        unsigned v = (threadIdx.x >= (unsigned)off) ? partial[threadIdx.x - off] : 0u;
        __syncthreads();
        partial[threadIdx.x] += v;
        __syncthreads();
    }
    unsigned run = partial[threadIdx.x] - ls;

#pragma unroll
    for (int j = 0; j < NBINS / 256; ++j) {
        unsigned c = local[j];
        if (c) {
            if (run < r1 && run + c >= r1) { bi[0] = lo + j; bi[2] = run; }
            if (run < r2 && run + c >= r2) { bi[1] = lo + j; }
        }
        run += c;
    }
}

// ---------- pass 3: fused candidate-compact + certain-intersection count ----------
__global__ __launch_bounds__(TPB, 4) void k_pass2(const float* __restrict__ pred,
                                                  const float* __restrict__ targ,
                                                  int nvec,
                                                  const unsigned* __restrict__ binfo,
                                                  unsigned* __restrict__ npairs,
                                                  unsigned* __restrict__ naa,
                                                  float2* __restrict__ pairs)
{
    __shared__ float2   sbuf[LCAP];
    __shared__ unsigned scnt, sbase;
    if (threadIdx.x == 0) scnt = 0;
    __syncthreads();

    const int b = blockIdx.y;
    const unsigned lo_t = binfo[(2 * b + 0) * 8 + 0], hi_t = binfo[(2 * b + 0) * 8 + 1];
    const unsigned lo_p = binfo[(2 * b + 1) * 8 + 0], hi_p = binfo[(2 * b + 1) * 8 + 1];

    const float4* __restrict__ p4 = (const float4*)pred + (size_t)b * nvec;
    const float4* __restrict__ t4 = (const float4*)targ + (size_t)b * nvec;

    unsigned laa = 0;
    const int S = BPB * TPB;

#define P2_PROC(tq, pq)                                                   \
    {                                                                     \
        float tv[4] = {tq.x, tq.y, tq.z, tq.w};                           \
        float pv[4] = {pq.x, pq.y, pq.z, pq.w};                           \
        _Pragma("unroll")                                                 \
        for (int j = 0; j < 4; ++j) {                                     \
            float tt = tv[j], pp = pv[j];                                 \
            if (tt > 0.01f) {                                             \
                unsigned at = bucketOf(tt);                               \
                bool t_in = (at >= lo_t) && (at <= hi_t);                 \
                bool t_ab = (at > hi_t);                                  \
                bool ppos = (pp > 0.f);                                   \
                unsigned ap = bucketOf(pp);                               \
                bool p_in = ppos && (ap >= lo_p) && (ap <= hi_p);         \
                bool p_ab = ppos && (ap > hi_p);                          \
                if (t_ab && p_ab) laa++;                                  \
                if (t_in || p_in) {                                       \
                    unsigned idx = atomicAdd(&scnt, 1u);                  \
                    if (idx < LCAP) sbuf[idx] = make_float2(tt, pp);      \
                }                                                         \
            }                                                             \
        }                                                                 \
    }

    int i = blockIdx.x * TPB + threadIdx.x;
    float4 cT0, cP0, cT1, cP1;
    cT0 = cP0 = cT1 = cP1 = make_float4(0.f, 0.f, 0.f, 0.f);
    if (i < nvec) {
        cT0 = t4[i]; cP0 = p4[i];
        if (i + S < nvec) { cT1 = t4[i + S]; cP1 = p4[i + S]; }
    }
    while (i < nvec) {
        const int nx = i + 2 * S;
        float4 nT0 = cT0, nP0 = cP0, nT1 = cT1, nP1 = cP1;
        if (nx < nvec)     { nT0 = t4[nx];     nP0 = p4[nx]; }
        if (nx + S < nvec) { nT1 = t4[nx + S]; nP1 = p4[nx + S]; }
        P2_PROC(cT0, cP0);
        if (i + S < nvec) P2_PROC(cT1, cP1);
        cT0 = nT0; cP0 = nP0; cT1 = nT1; cP1 = nP1;
        i = nx;
    }
#undef P2_PROC
    __syncthreads();
    if (threadIdx.x == 0) {
        unsigned n = scnt < LCAP ? scnt : LCAP;
        sbase = atomicAdd(&npairs[b], n);
        scnt = n;
    }
    __syncthreads();
    for (unsigned k = threadIdx.x; k < scnt; k += TPB) {
        unsigned idx = sbase + k;
        if (idx < PCAP) pairs[(size_t)b * PCAP + idx] = sbuf[k];
    }
    for (int off = 32; off; off >>= 1) laa += __shfl_down(laa, off);
    if ((threadIdx.x & 63) == 0 && laa) atomicAdd(&naa[b], laa);
}

// ---------- pass 4: sort candidates -> threshold + exact hot counts ----------
__global__ __launch_bounds__(256) void k_sortsel(const unsigned* __restrict__ binfo,
                                                 const unsigned* __restrict__ npairs,
                                                 const float2* __restrict__ pairs,
                                                 float* __restrict__ thr,
                                                 unsigned* __restrict__ hotc)
{
    __shared__ float s[SCAP];
    __shared__ unsigned scnt, sle;
    __shared__ float sth;

    const int bt = blockIdx.x;
    const int b = bt >> 1, t = bt & 1;
    const unsigned* bi = binfo + bt * 8;
    const unsigned nv = bi[5];
    if (nv == 0) {
        if (threadIdx.x == 0) { thr[bt] = 0.01f; hotc[bt] = 0; }
        return;
    }
    const unsigned lo = bi[0], hi = bi[1];
    if (threadIdx.x == 0) { scnt = 0; sle = 0; }
    __syncthreads();

    unsigned np = npairs[b]; if (np > PCAP) np = PCAP;
    for (unsigned i = threadIdx.x; i < np; i += 256) {
        float2 pr = pairs[(size_t)b * PCAP + i];
        float v = t ? pr.y : pr.x;
        if (v > 0.f) {
            unsigned a = bucketOf(v);
            if (a >= lo && a <= hi) {
                unsigned idx = atomicAdd(&scnt, 1u);
                if (idx < SCAP) s[idx] = v;
            }
        }
    }
    __syncthreads();
    unsigned n = scnt < SCAP ? scnt : SCAP;
    unsigned sn = 1; while (sn < n) sn <<= 1;
    if (sn < 2) sn = 2;
    for (unsigned i = n + threadIdx.x; i < sn; i += 256) s[i] = 3.402823466e+38f;
    __syncthreads();

    for (unsigned ksz = 2; ksz <= sn; ksz <<= 1) {
        for (unsigned j = ksz >> 1; j; j >>= 1) {
            for (unsigned i = threadIdx.x; i < sn; i += 256) {
                unsigned ixj = i ^ j;
                if (ixj > i) {
                    float a = s[i], c = s[ixj];
                    bool up = ((i & ksz) == 0);
                    if ((a > c) == up) { s[i] = c; s[ixj] = a; }
                }
            }
            __syncthreads();
        }
    }

    if (threadIdx.x == 0) {
        unsigned k = bi[3], cb = bi[2];
        float frac = __uint_as_float(bi[4]);
        long idx = (long)k - (long)cb;
        if (idx < 0) idx = 0;
        if (idx >= (long)n) idx = (long)n - 1;
        float v0 = s[idx];
        float v1 = (idx + 1 < (long)n) ? s[idx + 1] : v0;
        sth = v0 + frac * (v1 - v0);
        thr[bt] = sth;
    }
    __syncthreads();
    float th = sth;
    unsigned cle = 0;
    for (unsigned i = threadIdx.x; i < n; i += 256) if (s[i] <= th) cle++;
    for (int off = 32; off; off >>= 1) cle += __shfl_down(cle, off);
    if ((threadIdx.x & 63) == 0 && cle) atomicAdd(&sle, cle);
    __syncthreads();
    if (threadIdx.x == 0) {
        unsigned gle = bi[2] + sle;   // global count of masked values <= th
        hotc[bt] = nv - gle;
    }
}

// ---------- pass 5: resolve ambiguous pairs (one block per batch) ----------
__global__ __launch_bounds__(256) void k_resolve(const unsigned* __restrict__ npairs,
                                                 const float2* __restrict__ pairs,
                                                 const float* __restrict__ thr,
                                                 unsigned* __restrict__ iamb)
{
    __shared__ unsigned sI;
    if (threadIdx.x == 0) sI = 0;
    __syncthreads();
    const int b = blockIdx.x;
    float th_t = thr[2 * b + 0], th_p = thr[2 * b + 1];
    unsigned np = npairs[b]; if (np > PCAP) np = PCAP;
    unsigned c = 0;
    for (unsigned i = threadIdx.x; i < np; i += 256) {
        float2 pr = pairs[(size_t)b * PCAP + i];
        if (pr.x > th_t && pr.y > th_p) c++;
    }
    for (int off = 32; off; off >>= 1) c += __shfl_down(c, off);
    if ((threadIdx.x & 63) == 0 && c) atomicAdd(&sI, c);
    __syncthreads();
    if (threadIdx.x == 0) iamb[b] = sI;
}

// ---------- pass 6: combine ----------
__global__ void k_final(const double* __restrict__ sse,
                        const unsigned* __restrict__ nvalid,
                        const unsigned* __restrict__ naa,
                        const unsigned* __restrict__ iamb,
                        const unsigned* __restrict__ hotc,
                        float* __restrict__ out)
{
    if (threadIdx.x == 0 && blockIdx.x == 0) {
        double acc = 0.0;
        for (int b = 0; b < NB; ++b) {
            double nv  = (double)nvalid[2 * b + 0];
            double mse = sse[b] / (nv + 1e-8);
            double T = (double)hotc[2 * b + 0];
            double P = (double)hotc[2 * b + 1];
            double I = (double)(naa[b] + iamb[b]);
            double dice = 1.0 - 2.0 * I / (P + T + 1e-8);
            acc += 0.5 * mse + 0.5 * dice;
        }
        out[0] = (float)(acc / (double)NB);
    }
}

// ---------- launcher ----------
extern "C" void kernel_launch(void* const* d_in, const int* in_sizes, int n_in,
                              void* d_out, int out_size, void* d_ws, size_t ws_size,
                              hipStream_t stream) {
    const float* pred = (const float*)d_in[0];
    const float* targ = (const float*)d_in[1];
    float* out = (float*)d_out;

    const int total = in_sizes[0];
    const int N     = total / NB;   // 2,097,152
    const int nvec  = N / 4;        // 524,288

    // ws layout (bytes):
    // hist16: 8*128*2*1024*2 = 4,194,304
    // sse(64) nvalid(64) naa(64) npairs(64) binfo(512) thr(64) hotc(64) iamb(64)
    // pairs:  8*8192*8 = 524,288
    char* ws = (char*)d_ws;
    unsigned short* hist16 = (unsigned short*)(ws + 0);
    double*   sse    = (double*)  (ws + 4194304);
    unsigned* nvalid = (unsigned*)(ws + 4194368);
    unsigned* naa    = (unsigned*)(ws + 4194432);
    unsigned* npairs = (unsigned*)(ws + 4194496);
    unsigned* binfo  = (unsigned*)(ws + 4194560);
    float*    thr    = (float*)   (ws + 4195072);
    unsigned* hotc   = (unsigned*)(ws + 4195136);
    unsigned* iamb   = (unsigned*)(ws + 4195200);
    float2*   pairs  = (float2*)  (ws + 4195264);
    (void)ws_size; (void)n_in; (void)out_size;

    hipMemsetAsync(ws + 4194304, 0, 960, stream);  // accumulators only

    dim3 gs(BPB, NB);
    k_pass1  <<<gs, TPB, 0, stream>>>(pred, targ, nvec, hist16, sse, nvalid);
    k_scan   <<<2 * NB, 256, 0, stream>>>(hist16, nvalid, binfo);
    k_pass2  <<<gs, TPB, 0, stream>>>(pred, targ, nvec, binfo, npairs, naa, pairs);
    k_sortsel<<<2 * NB, 256, 0, stream>>>(binfo, npairs, pairs, thr, hotc);
    k_resolve<<<NB, 256, 0, stream>>>(npairs, pairs, thr, iamb);
    k_final  <<<1, 64, 0, stream>>>(sse, nvalid, naa, iamb, hotc, out);
}

// Round 5
// 180.646 us; speedup vs baseline: 1.9033x; 1.9033x over previous
//
#include <hip/hip_runtime.h>

#define NBINS 2048
#define BPB   64
#define TPB   256
#define NB    8
#define LCAP  512
#define PCAP  8192
#define SCAP  4096

static __device__ __forceinline__ unsigned bucketOf(float v) {
    unsigned b = (unsigned)(v * (float)NBINS);
    return b > (NBINS - 1) ? (NBINS - 1) : b;
}

// inline-asm global load: compiler cannot sink/serialize these
static __device__ __forceinline__ void gload4(float4& d, const float4* a) {
    asm volatile("global_load_dwordx4 %0, %1, off" : "=v"(d) : "v"(a));
}
#define WAIT_VMCNT(N)                                              \
    do {                                                           \
        asm volatile("s_waitcnt vmcnt(" #N ")" ::: "memory");      \
        __builtin_amdgcn_sched_barrier(0);                         \
    } while (0)

// issue 8 loads (4 strided float4 per tensor) into register set SET at chunk c
#define ISSUE(SET, c)                                              \
    do {                                                           \
        const float4* tb_ = t4 + i0 + (c) * 4 * S;                 \
        const float4* pb_ = p4 + i0 + (c) * 4 * S;                 \
        gload4(t##SET##0, tb_);         gload4(t##SET##1, tb_ + S);      \
        gload4(t##SET##2, tb_ + 2 * S); gload4(t##SET##3, tb_ + 3 * S);  \
        gload4(p##SET##0, pb_);         gload4(p##SET##1, pb_ + S);      \
        gload4(p##SET##2, pb_ + 2 * S); gload4(p##SET##3, pb_ + 3 * S);  \
    } while (0)

// ---------- pass 1: asm-pipelined streaming; LDS hist -> per-block u16 replicas ----------
__global__ __launch_bounds__(TPB) void k_pass1(const float* __restrict__ pred,
                                               const float* __restrict__ targ,
                                               int nvec,
                                               unsigned short* __restrict__ hist16,
                                               double* __restrict__ sse,
                                               unsigned* __restrict__ nvalid)
{
    __shared__ unsigned h[2 * NBINS];
    for (int k = threadIdx.x; k < 2 * NBINS; k += TPB) h[k] = 0u;
    __syncthreads();

    const int b = blockIdx.y;
    const float4* __restrict__ p4 = (const float4*)pred + (size_t)b * nvec;
    const float4* __restrict__ t4 = (const float4*)targ + (size_t)b * nvec;

    float    lsse = 0.f;
    unsigned lnv = 0, lnp = 0;
    const int S  = BPB * TPB;          // 16384
    const int i0 = blockIdx.x * TPB + threadIdx.x;

#define PEL1(tq, pq)                                             \
    {                                                            \
        float tv[4] = {tq.x, tq.y, tq.z, tq.w};                  \
        float pv[4] = {pq.x, pq.y, pq.z, pq.w};                  \
        _Pragma("unroll")                                        \
        for (int j = 0; j < 4; ++j) {                            \
            float tt = tv[j], pp = pv[j];                        \
            if (tt > 0.01f) {                                    \
                float d = pp - tt;                               \
                lsse += d * d; lnv++;                            \
                atomicAdd(&h[bucketOf(tt)], 1u);                 \
                if (pp > 0.f) {                                  \
                    lnp++;                                       \
                    atomicAdd(&h[NBINS + bucketOf(pp)], 1u);     \
                }                                                \
            }                                                    \
        }                                                        \
    }
#define PROC1(SET)                                               \
    {                                                            \
        PEL1(t##SET##0, p##SET##0); PEL1(t##SET##1, p##SET##1);  \
        PEL1(t##SET##2, p##SET##2); PEL1(t##SET##3, p##SET##3);  \
    }

    float4 tA0, tA1, tA2, tA3, pA0, pA1, pA2, pA3;
    float4 tB0, tB1, tB2, tB3, pB0, pB1, pB2, pB3;

    // exact trip: nvec == S*4*8 (524288) — 8 chunks, no tails
    ISSUE(A, 0);
    ISSUE(B, 1); WAIT_VMCNT(8); PROC1(A);
    ISSUE(A, 2); WAIT_VMCNT(8); PROC1(B);
    ISSUE(B, 3); WAIT_VMCNT(8); PROC1(A);
    ISSUE(A, 4); WAIT_VMCNT(8); PROC1(B);
    ISSUE(B, 5); WAIT_VMCNT(8); PROC1(A);
    ISSUE(A, 6); WAIT_VMCNT(8); PROC1(B);
    ISSUE(B, 7); WAIT_VMCNT(8); PROC1(A);
    WAIT_VMCNT(0); PROC1(B);
#undef PROC1
#undef PEL1
    __syncthreads();

    // plain coalesced u16 replica stores — every bin written, no memset needed
    unsigned short* gh = hist16 + ((size_t)b * BPB + blockIdx.x) * (2 * NBINS);
    ushort4* gh4 = (ushort4*)gh;
    for (int k = threadIdx.x; k < (2 * NBINS) / 4; k += TPB) {
        ushort4 v;
        v.x = (unsigned short)h[4 * k + 0];
        v.y = (unsigned short)h[4 * k + 1];
        v.z = (unsigned short)h[4 * k + 2];
        v.w = (unsigned short)h[4 * k + 3];
        gh4[k] = v;
    }

    for (int off = 32; off; off >>= 1) {
        lsse += __shfl_down(lsse, off);
        lnv  += __shfl_down(lnv, off);
        lnp  += __shfl_down(lnp, off);
    }
    if ((threadIdx.x & 63) == 0) {
        atomicAdd(&sse[b], (double)lsse);
        atomicAdd(&nvalid[2 * b + 0], lnv);
        atomicAdd(&nvalid[2 * b + 1], lnp);
    }
}

// ---------- pass 2: sum replicas, locate rank buckets ----------
// binfo per (b,t), 8 u32: [0]=lo [1]=hi [2]=cum_below [3]=k [4]=frac bits [5]=nv
__global__ __launch_bounds__(256) void k_scan(const unsigned short* __restrict__ hist16,
                                              const unsigned* __restrict__ nvalid,
                                              unsigned* __restrict__ binfo)
{
    const int bt = blockIdx.x;  // 0..15
    const int b = bt >> 1, t = bt & 1;
    const unsigned nv = nvalid[bt];
    unsigned* bi = binfo + bt * 8;

    __shared__ unsigned partial[256];
    __shared__ unsigned sk, sr2;

    if (threadIdx.x == 0) {
        bi[5] = nv;
        if (nv == 0) {
            bi[0] = 0xFFFFFFFFu; bi[1] = 0xFFFFFFFFu;
            bi[2] = 0; bi[3] = 0; bi[4] = __float_as_uint(0.0f);
        } else {
            double pos  = 0.9 * (double)(nv - 1);
            unsigned k  = (unsigned)pos;
            double frac = pos - (double)k;
            bi[3] = k;
            bi[4] = __float_as_uint((float)frac);
            sk = k;
            sr2 = (k + 2 <= nv) ? (k + 2) : (k + 1);
        }
    }
    __syncthreads();
    if (nv == 0) return;

    const unsigned r1 = sk + 1, r2 = sr2;

    const int lo = threadIdx.x * (NBINS / 256);  // 8 bins/thread
    unsigned local[NBINS / 256];
#pragma unroll
    for (int j = 0; j < NBINS / 256; ++j) local[j] = 0;
    for (int rep = 0; rep < BPB; ++rep) {
        const ushort4* h4 = (const ushort4*)(hist16 +
            ((size_t)b * BPB + rep) * (2 * NBINS) + (size_t)t * NBINS + lo);
        ushort4 a = h4[0], c = h4[1];
        local[0] += a.x; local[1] += a.y; local[2] += a.z; local[3] += a.w;
        local[4] += c.x; local[5] += c.y; local[6] += c.z; local[7] += c.w;
    }
    unsigned ls = 0;
#pragma unroll
    for (int j = 0; j < NBINS / 256; ++j) ls += local[j];

    partial[threadIdx.x] = ls;
    __syncthreads();
    for (int off = 1; off < 256; off <<= 1) {
        unsigned v = (threadIdx.x >= (unsigned)off) ? partial[threadIdx.x - off] : 0u;
        __syncthreads();
        partial[threadIdx.x] += v;
        __syncthreads();
    }
    unsigned run = partial[threadIdx.x] - ls;

#pragma unroll
    for (int j = 0; j < NBINS / 256; ++j) {
        unsigned c = local[j];
        if (c) {
            if (run < r1 && run + c >= r1) { bi[0] = lo + j; bi[2] = run; }
            if (run < r2 && run + c >= r2) { bi[1] = lo + j; }
        }
        run += c;
    }
}

// ---------- pass 3: fused candidate-compact + certain-intersection count ----------
__global__ __launch_bounds__(TPB) void k_pass2(const float* __restrict__ pred,
                                               const float* __restrict__ targ,
                                               int nvec,
                                               const unsigned* __restrict__ binfo,
                                               unsigned* __restrict__ npairs,
                                               unsigned* __restrict__ naa,
                                               float2* __restrict__ pairs)
{
    __shared__ float2   sbuf[LCAP];
    __shared__ unsigned scnt, sbase;
    if (threadIdx.x == 0) scnt = 0;
    __syncthreads();

    const int b = blockIdx.y;
    const unsigned lo_t = binfo[(2 * b + 0) * 8 + 0], hi_t = binfo[(2 * b + 0) * 8 + 1];
    const unsigned lo_p = binfo[(2 * b + 1) * 8 + 0], hi_p = binfo[(2 * b + 1) * 8 + 1];

    const float4* __restrict__ p4 = (const float4*)pred + (size_t)b * nvec;
    const float4* __restrict__ t4 = (const float4*)targ + (size_t)b * nvec;

    unsigned laa = 0;
    const int S  = BPB * TPB;
    const int i0 = blockIdx.x * TPB + threadIdx.x;

#define PEL2(tq, pq)                                                      \
    {                                                                     \
        float tv[4] = {tq.x, tq.y, tq.z, tq.w};                           \
        float pv[4] = {pq.x, pq.y, pq.z, pq.w};                           \
        _Pragma("unroll")                                                 \
        for (int j = 0; j < 4; ++j) {                                     \
            float tt = tv[j], pp = pv[j];                                 \
            if (tt > 0.01f) {                                             \
                unsigned at = bucketOf(tt);                               \
                bool t_in = (at >= lo_t) && (at <= hi_t);                 \
                bool t_ab = (at > hi_t);                                  \
                bool ppos = (pp > 0.f);                                   \
                unsigned ap = bucketOf(pp);                               \
                bool p_in = ppos && (ap >= lo_p) && (ap <= hi_p);         \
                bool p_ab = ppos && (ap > hi_p);                          \
                if (t_ab && p_ab) laa++;                                  \
                if (t_in || p_in) {                                       \
                    unsigned idx = atomicAdd(&scnt, 1u);                  \
                    if (idx < LCAP) sbuf[idx] = make_float2(tt, pp);      \
                }                                                         \
            }                                                             \
        }                                                                 \
    }
#define PROC2(SET)                                               \
    {                                                            \
        PEL2(t##SET##0, p##SET##0); PEL2(t##SET##1, p##SET##1);  \
        PEL2(t##SET##2, p##SET##2); PEL2(t##SET##3, p##SET##3);  \
    }

    float4 tA0, tA1, tA2, tA3, pA0, pA1, pA2, pA3;
    float4 tB0, tB1, tB2, tB3, pB0, pB1, pB2, pB3;

    ISSUE(A, 0);
    ISSUE(B, 1); WAIT_VMCNT(8); PROC2(A);
    ISSUE(A, 2); WAIT_VMCNT(8); PROC2(B);
    ISSUE(B, 3); WAIT_VMCNT(8); PROC2(A);
    ISSUE(A, 4); WAIT_VMCNT(8); PROC2(B);
    ISSUE(B, 5); WAIT_VMCNT(8); PROC2(A);
    ISSUE(A, 6); WAIT_VMCNT(8); PROC2(B);
    ISSUE(B, 7); WAIT_VMCNT(8); PROC2(A);
    WAIT_VMCNT(0); PROC2(B);
#undef PROC2
#undef PEL2
    __syncthreads();
    if (threadIdx.x == 0) {
        unsigned n = scnt < LCAP ? scnt : LCAP;
        sbase = atomicAdd(&npairs[b], n);
        scnt = n;
    }
    __syncthreads();
    for (unsigned k = threadIdx.x; k < scnt; k += TPB) {
        unsigned idx = sbase + k;
        if (idx < PCAP) pairs[(size_t)b * PCAP + idx] = sbuf[k];
    }
    for (int off = 32; off; off >>= 1) laa += __shfl_down(laa, off);
    if ((threadIdx.x & 63) == 0 && laa) atomicAdd(&naa[b], laa);
}

// ---------- pass 4: sort candidates -> threshold + exact hot counts ----------
__global__ __launch_bounds__(1024) void k_sortsel(const unsigned* __restrict__ binfo,
                                                  const unsigned* __restrict__ npairs,
                                                  const float2* __restrict__ pairs,
                                                  float* __restrict__ thr,
                                                  unsigned* __restrict__ hotc)
{
    __shared__ float s[SCAP];
    __shared__ unsigned scnt, sle;
    __shared__ float sth;

    const int bt = blockIdx.x;
    const int b = bt >> 1, t = bt & 1;
    const unsigned* bi = binfo + bt * 8;
    const unsigned nv = bi[5];
    if (nv == 0) {
        if (threadIdx.x == 0) { thr[bt] = 0.01f; hotc[bt] = 0; }
        return;
    }
    const unsigned lo = bi[0], hi = bi[1];
    if (threadIdx.x == 0) { scnt = 0; sle = 0; }
    __syncthreads();

    unsigned np = npairs[b]; if (np > PCAP) np = PCAP;
    for (unsigned i = threadIdx.x; i < np; i += 1024) {
        float2 pr = pairs[(size_t)b * PCAP + i];
        float v = t ? pr.y : pr.x;
        if (v > 0.f) {
            unsigned a = bucketOf(v);
            if (a >= lo && a <= hi) {
                unsigned idx = atomicAdd(&scnt, 1u);
                if (idx < SCAP) s[idx] = v;
            }
        }
    }
    __syncthreads();
    unsigned n = scnt < SCAP ? scnt : SCAP;
    unsigned sn = 1; while (sn < n) sn <<= 1;
    if (sn < 2) sn = 2;
    for (unsigned i = n + threadIdx.x; i < sn; i += 1024) s[i] = 3.402823466e+38f;
    __syncthreads();

    for (unsigned ksz = 2; ksz <= sn; ksz <<= 1) {
        for (unsigned j = ksz >> 1; j; j >>= 1) {
            for (unsigned i = threadIdx.x; i < sn; i += 1024) {
                unsigned ixj = i ^ j;
                if (ixj > i) {
                    float a = s[i], c = s[ixj];
                    bool up = ((i & ksz) == 0);
                    if ((a > c) == up) { s[i] = c; s[ixj] = a; }
                }
            }
            __syncthreads();
        }
    }

    if (threadIdx.x == 0) {
        unsigned k = bi[3], cb = bi[2];
        float frac = __uint_as_float(bi[4]);
        long idx = (long)k - (long)cb;
        if (idx < 0) idx = 0;
        if (idx >= (long)n) idx = (long)n - 1;
        float v0 = s[idx];
        float v1 = (idx + 1 < (long)n) ? s[idx + 1] : v0;
        sth = v0 + frac * (v1 - v0);
        thr[bt] = sth;
    }
    __syncthreads();
    float th = sth;
    unsigned cle = 0;
    for (unsigned i = threadIdx.x; i < n; i += 1024) if (s[i] <= th) cle++;
    for (int off = 32; off; off >>= 1) cle += __shfl_down(cle, off);
    if ((threadIdx.x & 63) == 0 && cle) atomicAdd(&sle, cle);
    __syncthreads();
    if (threadIdx.x == 0) {
        unsigned gle = bi[2] + sle;   // global count of masked values <= th
        hotc[bt] = nv - gle;
    }
}

// ---------- pass 5: resolve ambiguous pairs + combine loss ----------
__global__ __launch_bounds__(256) void k_final(const double* __restrict__ sse,
                                               const unsigned* __restrict__ nvalid,
                                               const unsigned* __restrict__ naa,
                                               const unsigned* __restrict__ npairs,
                                               const float2* __restrict__ pairs,
                                               const float* __restrict__ thr,
                                               const unsigned* __restrict__ hotc,
                                               float* __restrict__ out)
{
    __shared__ unsigned sI;
    __shared__ double acc;
    if (threadIdx.x == 0) acc = 0.0;
    for (int b = 0; b < NB; ++b) {
        if (threadIdx.x == 0) sI = 0;
        __syncthreads();
        float th_t = thr[2 * b + 0], th_p = thr[2 * b + 1];
        unsigned np = npairs[b]; if (np > PCAP) np = PCAP;
        unsigned c = 0;
        for (unsigned i = threadIdx.x; i < np; i += 256) {
            float2 pr = pairs[(size_t)b * PCAP + i];
            if (pr.x > th_t && pr.y > th_p) c++;
        }
        for (int off = 32; off; off >>= 1) c += __shfl_down(c, off);
        if ((threadIdx.x & 63) == 0 && c) atomicAdd(&sI, c);
        __syncthreads();
        if (threadIdx.x == 0) {
            double nv  = (double)nvalid[2 * b + 0];
            double mse = sse[b] / (nv + 1e-8);
            double T = (double)hotc[2 * b + 0];
            double P = (double)hotc[2 * b + 1];
            double I = (double)(naa[b] + sI);
            double dice = 1.0 - 2.0 * I / (P + T + 1e-8);
            acc += 0.5 * mse + 0.5 * dice;
        }
        __syncthreads();
    }
    if (threadIdx.x == 0) out[0] = (float)(acc / (double)NB);
}

// ---------- launcher ----------
extern "C" void kernel_launch(void* const* d_in, const int* in_sizes, int n_in,
                              void* d_out, int out_size, void* d_ws, size_t ws_size,
                              hipStream_t stream) {
    const float* pred = (const float*)d_in[0];
    const float* targ = (const float*)d_in[1];
    float* out = (float*)d_out;

    const int total = in_sizes[0];
    const int N     = total / NB;   // 2,097,152
    const int nvec  = N / 4;        // 524,288 == BPB*TPB*4*8 exactly

    // ws layout (bytes):
    // hist16: 8*64*2*2048*2 = 4,194,304
    // sse(64) nvalid(64) naa(64) npairs(64) binfo(512) thr(64) hotc(64)
    // pairs:  8*8192*8 = 524,288
    char* ws = (char*)d_ws;
    unsigned short* hist16 = (unsigned short*)(ws + 0);
    double*   sse    = (double*)  (ws + 4194304);
    unsigned* nvalid = (unsigned*)(ws + 4194368);
    unsigned* naa    = (unsigned*)(ws + 4194432);
    unsigned* npairs = (unsigned*)(ws + 4194496);
    unsigned* binfo  = (unsigned*)(ws + 4194560);
    float*    thr    = (float*)   (ws + 4195072);
    unsigned* hotc   = (unsigned*)(ws + 4195136);
    float2*   pairs  = (float2*)  (ws + 4195200);
    (void)ws_size; (void)n_in; (void)out_size;

    hipMemsetAsync(ws + 4194304, 0, 256, stream);  // sse+nvalid+naa+npairs only

    dim3 gs(BPB, NB);
    k_pass1  <<<gs, TPB, 0, stream>>>(pred, targ, nvec, hist16, sse, nvalid);
    k_scan   <<<2 * NB, 256, 0, stream>>>(hist16, nvalid, binfo);
    k_pass2  <<<gs, TPB, 0, stream>>>(pred, targ, nvec, binfo, npairs, naa, pairs);
    k_sortsel<<<2 * NB, 1024, 0, stream>>>(binfo, npairs, pairs, thr, hotc);
    k_final  <<<1, 256, 0, stream>>>(sse, nvalid, naa, npairs, pairs, thr, hotc, out);
}